// Round 1
// baseline (555.446 us; speedup 1.0000x reference)
//
#include <hip/hip_runtime.h>
#include <stdint.h>

typedef __attribute__((ext_vector_type(8))) short short8;
typedef __attribute__((ext_vector_type(4))) float f32x4;

#define DEVFN static __device__ __forceinline__

// ---------------- helpers ----------------
DEVFN float bf2f(uint16_t u) { union { uint32_t i; float f; } v; v.i = ((uint32_t)u) << 16; return v.f; }
DEVFN uint16_t f2bf(float f) {
  union { float f; uint32_t i; } v; v.f = f;
  uint32_t u = v.i;
  u += 0x7fffu + ((u >> 16) & 1u);   // RNE
  return (uint16_t)(u >> 16);
}
DEVFN int imin(int a, int b) { return a < b ? a : b; }

DEVFN void gl_lds16(const void* g, void* l) {
  // async global->LDS, 16B per lane; LDS dst = wave-uniform base + lane*16
  __builtin_amdgcn_global_load_lds(
      (__attribute__((address_space(1))) void*)(void*)g,
      (__attribute__((address_space(3))) void*)l, 16, 0, 0);
}

DEVFN f32x4 mfma16(short8 a, short8 b, f32x4 c) {
  return __builtin_amdgcn_mfma_f32_16x16x32_bf16(a, b, c, 0, 0, 0);
}

// ---------------- workspace layout (bytes) ----------------
static constexpr size_t OFF_XP   = 0;          // bf16 [64][232][232][4]  x: masked, padded(+3), NHWC4
static constexpr size_t OFF_W1T  = 27557888;   // bf16 [7][64][32]        w1t[kh][oc][kw*4+ic]
static constexpr size_t OFF_W2T  = 27586560;   // bf16 [49][768][64]      w2t[kh*7+kw][oc][ic]
static constexpr size_t OFF_Y1   = 32403456;   // bf16 [64][112][112][64] conv1 out (active cells only)
static constexpr size_t OFF_P1   = 135163904;  // bf16 [64][62][62][64]   pool1 out, padded(+3), NHWC
static constexpr size_t OFF_Y2   = 166653952;  // bf16 [64][28][28][768]  conv2 out (active cells only)
static constexpr size_t OFF_LIST = 243724288;  // int [12544] active cell list (b*196+cell)
static constexpr size_t OFF_CNT  = 243774464;  // int count
static constexpr size_t WS_NEED  = 243774468;

// ---------------- stage 0: active-cell list ----------------
__global__ __launch_bounds__(256) void k_list(const int* __restrict__ masks,
                                              int* __restrict__ list, int* __restrict__ count) {
  int gid = blockIdx.x * 256 + threadIdx.x;   // 49*256 = 12544 exactly
  if (masks[gid]) {
    int p = atomicAdd(count, 1);
    list[p] = gid;
  }
}

// ---------------- stage 1: x -> masked bf16 NHWC4 padded ----------------
__global__ __launch_bounds__(256) void k_prep(const float* __restrict__ x, const int* __restrict__ masks,
                                              uint16_t* __restrict__ xp) {
  int gid = blockIdx.x * 256 + threadIdx.x;   // 64*232*232 = 3,444,736 exactly
  int b = gid / 53824;
  int rc = gid - b * 53824;
  int r2 = rc / 232;
  int c2 = rc - r2 * 232;
  int r = r2 - 3, c = c2 - 3;
  uint16_t o0 = 0, o1 = 0, o2 = 0;
  if ((unsigned)r < 224u && (unsigned)c < 224u) {
    if (masks[b * 196 + (r >> 4) * 14 + (c >> 4)]) {
      const float* px = x + (((size_t)b * 3) * 224 + r) * 224 + c;
      o0 = f2bf(px[0]);
      o1 = f2bf(px[50176]);
      o2 = f2bf(px[100352]);
    }
  }
  ushort4 o; o.x = o0; o.y = o1; o.z = o2; o.w = 0;
  *(ushort4*)(xp + (size_t)gid * 4) = o;
}

// ---------------- stage 2: weight transforms ----------------
__global__ __launch_bounds__(256) void k_wt(const float* __restrict__ w1, const float* __restrict__ w2,
                                            uint16_t* __restrict__ w1t, uint16_t* __restrict__ w2t) {
  int gid = blockIdx.x * 256 + threadIdx.x;   // 14336 + 2408448 = 2,422,784 exactly
  if (gid < 14336) {
    int kh = gid / 2048; int r = gid - kh * 2048;
    int oc = r >> 5, slot = r & 31;
    int kw = slot >> 2, ic = slot & 3;
    float v = 0.f;
    if (kw < 7 && ic < 3) v = w1[((oc * 3 + ic) * 7 + kh) * 7 + kw];
    w1t[gid] = f2bf(v);
  } else {
    int g2 = gid - 14336;
    int khw = g2 / 49152; int r = g2 - khw * 49152;
    int oc = r >> 6, ic = r & 63;
    int kh = khw / 7, kw = khw - kh * 7;
    w2t[g2] = f2bf(w2[((oc * 64 + ic) * 7 + kh) * 7 + kw]);
  }
}

// ---------------- stage 3: conv1 (7x7 s2) via MFMA, active cells only ----------------
// M-tile = 2 cells * 64 positions = 128, N = 64 oc, K = 7 kh-steps of 32 (8 kw-slots * 4 ch)
__global__ __launch_bounds__(256) void k_conv1(const uint16_t* __restrict__ xp, const uint16_t* __restrict__ w1t,
                                               const int* __restrict__ list, const int* __restrict__ count,
                                               uint16_t* __restrict__ y1) {
  __shared__ uint16_t sB[7 * 64 * 32];   // 28 KB: whole w1t resident
  __shared__ uint16_t sA[128 * 32];      // 8 KB
  __shared__ int sc[2];

  int cnt = *count;
  int blk = blockIdx.x;
  if (blk * 2 >= cnt) return;
  int tid = threadIdx.x, lane = tid & 63, wave = tid >> 6;

  // stage all of w1t -> sB (1792 x 16B chunks)
  {
    const char* wg = (const char*)w1t;
    char* wl = (char*)sB;
#pragma unroll
    for (int t = 0; t < 7; ++t) {
      int off = t * 4096 + wave * 1024;
      gl_lds16(wg + off + lane * 16, wl + off);
    }
  }
  if (tid < 2) sc[tid] = list[imin(blk * 2 + tid, cnt - 1)];
  __syncthreads();

  // per-lane A staging addresses (2 rows per lane)
  const char* gA[2];
#pragma unroll
  for (int t = 0; t < 2; ++t) {
    int r = wave * 32 + t * 16 + (lane >> 2);
    int cell = sc[r >> 6];
    int b = cell / 196, cc = cell - b * 196;
    int ci = cc / 14, cj = cc - ci * 14;
    int p = r & 63;
    int oh = ci * 8 + (p >> 3), ow = cj * 8 + (p & 7);
    gA[t] = (const char*)xp + (((size_t)(b * 232 + 2 * oh)) * 232 + 2 * ow) * 8 + (lane & 3) * 16;
  }

  f32x4 acc[2][4];
#pragma unroll
  for (int i = 0; i < 2; ++i)
#pragma unroll
    for (int j = 0; j < 4; ++j) acc[i][j] = f32x4{0.f, 0.f, 0.f, 0.f};

  int wm = wave * 32;
  int mrow = lane & 15, kg = lane >> 4;

#pragma unroll 1
  for (int kh = 0; kh < 7; ++kh) {
    char* la = (char*)sA + wm * 64;
    gl_lds16(gA[0] + kh * 1856, la);
    gl_lds16(gA[1] + kh * 1856, la + 1024);
    __syncthreads();
    const uint16_t* Bk = sB + kh * 2048;
    short8 a0 = *(const short8*)(sA + (wm + mrow) * 32 + kg * 8);
    short8 a1 = *(const short8*)(sA + (wm + 16 + mrow) * 32 + kg * 8);
#pragma unroll
    for (int j = 0; j < 4; ++j) {
      short8 bj = *(const short8*)(Bk + (16 * j + mrow) * 32 + kg * 8);
      acc[0][j] = mfma16(a0, bj, acc[0][j]);
      acc[1][j] = mfma16(a1, bj, acc[1][j]);
    }
    __syncthreads();
  }

  // epilogue: relu, write NHWC bf16 (mask is 1 on all rows here)
#pragma unroll
  for (int i = 0; i < 2; ++i) {
    int rbase = wm + 16 * i;
    int cellidx = blk * 2 + (rbase >> 6);
    if (cellidx >= cnt) continue;
    int cell = sc[rbase >> 6];
    int b = cell / 196, cc = cell - b * 196;
    int ci = cc / 14, cj = cc - ci * 14;
#pragma unroll
    for (int j = 0; j < 4; ++j) {
      int oc = 16 * j + mrow;
#pragma unroll
      for (int r = 0; r < 4; ++r) {
        int row = rbase + kg * 4 + r;
        int p = row & 63;
        int oh = ci * 8 + (p >> 3), ow = cj * 8 + (p & 7);
        float v = acc[i][j][r];
        v = v > 0.f ? v : 0.f;
        y1[(((size_t)(b * 112 + oh)) * 112 + ow) * 64 + oc] = f2bf(v);
      }
    }
  }
}

// ---------------- stage 4: MaxBlurPool1 (112 -> 56), mask-aware, writes padded p1 ----------------
__global__ __launch_bounds__(256) void k_pool1(const uint16_t* __restrict__ y1, const int* __restrict__ masks,
                                               uint16_t* __restrict__ p1) {
  __shared__ uint16_t sY[18 * 18 * 64];  // 41,472 B
  int b = blockIdx.y;
  int tile = blockIdx.x;                 // 64 tiles of 8x8 over padded 62x62
  int tr = tile >> 3, tc = tile & 7;
  int pr0 = tr * 8, pc0 = tc * 8;
  int R0 = 2 * pr0 - 7, C0 = 2 * pc0 - 7;  // staged y1 origin (padded coords -3, then 2*oh-1)
  int tid = threadIdx.x;
  const int* mb = masks + b * 196;

  for (int idx = tid; idx < 2592; idx += 256) {   // 324 pixels * 8 chunks
    int pix = idx >> 3, ch = idx & 7;
    int pr = pix / 18, pc = pix - pr * 18;
    int r = R0 + pr, c = C0 + pc;
    short8 v = {0, 0, 0, 0, 0, 0, 0, 0};
    if ((unsigned)r < 112u && (unsigned)c < 112u && mb[(r >> 3) * 14 + (c >> 3)])
      v = *(const short8*)(y1 + (((size_t)(b * 112 + r)) * 112 + c) * 64 + ch * 8);
    *(short8*)(sY + ((size_t)(pr * 18 + pc)) * 64 + ch * 8) = v;
  }
  __syncthreads();

  for (int it = tid; it < 512; it += 256) {
    int opix = it >> 3, ch = it & 7;
    int lr = opix >> 3, lc = opix & 7;
    int pr = pr0 + lr, pc = pc0 + lc;
    if (pr >= 62 || pc >= 62) continue;
    int oh = pr - 3, ow = pc - 3;
    float acc[8] = {0.f, 0.f, 0.f, 0.f, 0.f, 0.f, 0.f, 0.f};
    if ((unsigned)oh < 56u && (unsigned)ow < 56u) {
      float hm_prev[3][8];
#pragma unroll
      for (int dd = 0; dd < 4; ++dd) {
        float yv[4][8];
        const uint16_t* src = sY + ((size_t)((2 * lr + dd) * 18 + 2 * lc)) * 64 + ch * 8;
#pragma unroll
        for (int e = 0; e < 4; ++e) {
          short8 t8 = *(const short8*)(src + e * 64);
#pragma unroll
          for (int k = 0; k < 8; ++k) yv[e][k] = bf2f((uint16_t)t8[k]);
        }
        float hm[3][8];
#pragma unroll
        for (int e = 0; e < 3; ++e) {
          int qc = 2 * ow - 1 + e;
          float cv = ((unsigned)qc <= 110u) ? 1.f : 0.f;
#pragma unroll
          for (int k = 0; k < 8; ++k) hm[e][k] = cv * fmaxf(yv[e][k], yv[e + 1][k]);
        }
        if (dd > 0) {
          int d = dd - 1;
          int qr = 2 * oh - 1 + d;
          if ((unsigned)qr <= 110u) {
            float wd = (d == 1) ? 2.f : 1.f;
#pragma unroll
            for (int e = 0; e < 3; ++e) {
              float w = wd * ((e == 1) ? 2.f : 1.f);
#pragma unroll
              for (int k = 0; k < 8; ++k) acc[k] += w * fmaxf(hm_prev[e][k], hm[e][k]);
            }
          }
        }
#pragma unroll
        for (int e = 0; e < 3; ++e)
#pragma unroll
          for (int k = 0; k < 8; ++k) hm_prev[e][k] = hm[e][k];
      }
#pragma unroll
      for (int k = 0; k < 8; ++k) acc[k] *= (1.f / 16.f);
    }
    short8 o;
#pragma unroll
    for (int k = 0; k < 8; ++k) o[k] = (short)f2bf(acc[k]);
    *(short8*)(p1 + (((size_t)(b * 62 + pr)) * 62 + pc) * 64 + ch * 8) = o;
  }
}

// ---------------- stage 5: conv2 (7x7 s2) via MFMA, active cells only ----------------
// M-tile = 32 cells * 4 positions = 128, N-tile = 128 of 768 oc, K = 49 steps of 64 (ic)
__global__ __launch_bounds__(256) void k_conv2(const uint16_t* __restrict__ p1, const uint16_t* __restrict__ w2t,
                                               const int* __restrict__ list, const int* __restrict__ count,
                                               uint16_t* __restrict__ y2) {
  __shared__ uint16_t sA[128 * 64];   // 16 KB  A[row][ic]
  __shared__ uint16_t sBt[128 * 64];  // 16 KB  B^T[oc][ic]
  __shared__ int sc[32];

  int cnt = *count;
  int mt = blockIdx.x;
  if (mt * 32 >= cnt) return;
  int tid = threadIdx.x, lane = tid & 63, wave = tid >> 6;
  int ocb = blockIdx.y * 128;

  if (tid < 32) sc[tid] = list[imin(mt * 32 + tid, cnt - 1)];
  __syncthreads();

  const char* gA[4]; const char* gB[4];
#pragma unroll
  for (int t = 0; t < 4; ++t) {
    int r = wave * 32 + t * 8 + (lane >> 3);
    int cell = sc[r >> 2];
    int b = cell / 196, cc = cell - b * 196;
    int ci = cc / 14, cj = cc - ci * 14;
    int p = r & 3;
    int oh = 2 * ci + (p >> 1), ow = 2 * cj + (p & 1);
    gA[t] = (const char*)p1 + (((size_t)(b * 62 + 2 * oh)) * 62 + 2 * ow) * 128 + (lane & 7) * 16;
    int ocr = ocb + wave * 32 + t * 8 + (lane >> 3);
    gB[t] = (const char*)w2t + (size_t)ocr * 128 + (lane & 7) * 16;
  }

  f32x4 acc[4][4];
#pragma unroll
  for (int i = 0; i < 4; ++i)
#pragma unroll
    for (int j = 0; j < 4; ++j) acc[i][j] = f32x4{0.f, 0.f, 0.f, 0.f};

  int wm = (wave >> 1) * 64, wn = (wave & 1) * 64;
  int mrow = lane & 15, kg = lane >> 4;
  int kh = 0, kw = 0;

#pragma unroll 1
  for (int it = 0; it < 49; ++it) {
    size_t offA = (size_t)(kh * 62 + kw) * 128;
    size_t offB = (size_t)it * 98304;   // 768*128 B per (kh,kw) slice
    char* la = (char*)sA + (wave * 32) * 128;
    char* lb = (char*)sBt + (wave * 32) * 128;
#pragma unroll
    for (int t = 0; t < 4; ++t) {
      gl_lds16(gA[t] + offA, la + t * 1024);
      gl_lds16(gB[t] + offB, lb + t * 1024);
    }
    __syncthreads();
#pragma unroll
    for (int ks = 0; ks < 2; ++ks) {
      short8 a[4], bb[4];
#pragma unroll
      for (int i = 0; i < 4; ++i)
        a[i] = *(const short8*)(sA + (wm + 16 * i + mrow) * 64 + ks * 32 + kg * 8);
#pragma unroll
      for (int j = 0; j < 4; ++j)
        bb[j] = *(const short8*)(sBt + (wn + 16 * j + mrow) * 64 + ks * 32 + kg * 8);
#pragma unroll
      for (int i = 0; i < 4; ++i)
#pragma unroll
        for (int j = 0; j < 4; ++j)
          acc[i][j] = mfma16(a[i], bb[j], acc[i][j]);
    }
    __syncthreads();
    if (++kw == 7) { kw = 0; ++kh; }
  }

  // epilogue: relu, write y2 NHWC bf16 (active rows only)
#pragma unroll
  for (int i = 0; i < 4; ++i) {
    int rbase = wm + 16 * i;
    int cellslot = (rbase >> 2) + kg;
    int cellidx = mt * 32 + cellslot;
    if (cellidx >= cnt) continue;
    int cell = sc[cellslot];
    int b = cell / 196, cc = cell - b * 196;
    int ci = cc / 14, cj = cc - ci * 14;
#pragma unroll
    for (int j = 0; j < 4; ++j) {
      int oc = ocb + wn + 16 * j + mrow;
#pragma unroll
      for (int r = 0; r < 4; ++r) {
        int oh = 2 * ci + (r >> 1), ow = 2 * cj + (r & 1);
        float v = acc[i][j][r];
        v = v > 0.f ? v : 0.f;
        y2[(((size_t)(b * 784)) + oh * 28 + ow) * 768 + oc] = f2bf(v);
      }
    }
  }
}

// ---------------- stage 6: MaxBlurPool2 (28 -> 14) + transpose to [B,196,768] fp32 ----------------
__global__ __launch_bounds__(256) void k_pool2(const uint16_t* __restrict__ y2, const int* __restrict__ masks,
                                               float* __restrict__ out) {
  int gid = blockIdx.x * 256 + threadIdx.x;   // 64*14*192 = 172,032 exactly
  int b = gid / 2688;
  int r2 = gid - b * 2688;
  int pi = r2 / 192;
  int cg = r2 - pi * 192;
  int ch0 = cg * 4;
  const int* mb = masks + b * 196;

  float acc[14][4];
#pragma unroll
  for (int p = 0; p < 14; ++p)
#pragma unroll
    for (int u = 0; u < 4; ++u) acc[p][u] = 0.f;

  float vmp[3][4];
#pragma unroll
  for (int c = 0; c < 28; ++c) {
    int cellj = c >> 1;
    float rowv[4][4];
#pragma unroll
    for (int k = 0; k < 4; ++k) {
      int r = 2 * pi - 1 + k;
      bool v = ((unsigned)r < 28u) && mb[(r >> 1) * 14 + cellj];
      if (v) {
        const uint16_t* src = y2 + (((size_t)(b * 784)) + r * 28 + c) * 768 + ch0;
        ushort4 t = *(const ushort4*)src;
        rowv[k][0] = bf2f(t.x); rowv[k][1] = bf2f(t.y); rowv[k][2] = bf2f(t.z); rowv[k][3] = bf2f(t.w);
      } else {
        rowv[k][0] = 0.f; rowv[k][1] = 0.f; rowv[k][2] = 0.f; rowv[k][3] = 0.f;
      }
    }
    float vm[3][4];
#pragma unroll
    for (int k = 0; k < 3; ++k) {
      int q = 2 * pi - 1 + k;
      float rv = ((unsigned)q <= 26u) ? 1.f : 0.f;
#pragma unroll
      for (int u = 0; u < 4; ++u) vm[k][u] = rv * fmaxf(rowv[k][u], rowv[k + 1][u]);
    }
    if (c > 0) {
      int qj = c - 1;
      float bv[4];
#pragma unroll
      for (int u = 0; u < 4; ++u) {
        float h0 = fmaxf(vmp[0][u], vm[0][u]);
        float h1 = fmaxf(vmp[1][u], vm[1][u]);
        float h2 = fmaxf(vmp[2][u], vm[2][u]);
        bv[u] = h0 + 2.f * h1 + h2;
      }
      if ((qj & 1) == 0) {
        int p = qj >> 1;
#pragma unroll
        for (int u = 0; u < 4; ++u) acc[p][u] += 2.f * bv[u];
      } else {
        int p0 = (qj - 1) >> 1, p1 = p0 + 1;
#pragma unroll
        for (int u = 0; u < 4; ++u) acc[p0][u] += bv[u];
        if (p1 < 14) {
#pragma unroll
          for (int u = 0; u < 4; ++u) acc[p1][u] += bv[u];
        }
      }
    }
#pragma unroll
    for (int k = 0; k < 3; ++k)
#pragma unroll
      for (int u = 0; u < 4; ++u) vmp[k][u] = vm[k][u];
  }

#pragma unroll
  for (int p = 0; p < 14; ++p) {
    float4 o;
    o.x = acc[p][0] * (1.f / 16.f);
    o.y = acc[p][1] * (1.f / 16.f);
    o.z = acc[p][2] * (1.f / 16.f);
    o.w = acc[p][3] * (1.f / 16.f);
    *(float4*)(out + (((size_t)(b * 196)) + pi * 14 + p) * 768 + ch0) = o;
  }
}

// ---------------- launcher ----------------
extern "C" void kernel_launch(void* const* d_in, const int* in_sizes, int n_in,
                              void* d_out, int out_size, void* d_ws, size_t ws_size,
                              hipStream_t stream) {
  const float* x     = (const float*)d_in[0];
  const int*   masks = (const int*)d_in[1];
  const float* w1    = (const float*)d_in[2];
  const float* w2    = (const float*)d_in[3];

  char* ws = (char*)d_ws;
  if (ws_size < WS_NEED) return;  // fail loudly (output stays poisoned) rather than corrupt memory

  uint16_t* xp  = (uint16_t*)(ws + OFF_XP);
  uint16_t* w1t = (uint16_t*)(ws + OFF_W1T);
  uint16_t* w2t = (uint16_t*)(ws + OFF_W2T);
  uint16_t* y1  = (uint16_t*)(ws + OFF_Y1);
  uint16_t* p1  = (uint16_t*)(ws + OFF_P1);
  uint16_t* y2  = (uint16_t*)(ws + OFF_Y2);
  int* list     = (int*)(ws + OFF_LIST);
  int* cnt      = (int*)(ws + OFF_CNT);

  hipMemsetAsync(cnt, 0, 4, stream);
  k_list<<<49, 256, 0, stream>>>(masks, list, cnt);
  k_prep<<<13456, 256, 0, stream>>>(x, masks, xp);
  k_wt<<<9464, 256, 0, stream>>>(w1, w2, w1t, w2t);
  k_conv1<<<6272, 256, 0, stream>>>(xp, w1t, list, cnt, y1);
  k_pool1<<<dim3(64, 64), 256, 0, stream>>>(y1, masks, p1);
  k_conv2<<<dim3(392, 6), 256, 0, stream>>>(p1, w2t, list, cnt, y2);
  k_pool2<<<672, 256, 0, stream>>>(y2, masks, (float*)d_out);
}

// Round 2
// 418.901 us; speedup vs baseline: 1.3260x; 1.3260x over previous
//
#include <hip/hip_runtime.h>
#include <stdint.h>

typedef __attribute__((ext_vector_type(8))) short short8;
typedef __attribute__((ext_vector_type(4))) float f32x4;

#define DEVFN static __device__ __forceinline__

// ---------------- helpers ----------------
DEVFN float bf2f(uint16_t u) { union { uint32_t i; float f; } v; v.i = ((uint32_t)u) << 16; return v.f; }
DEVFN uint16_t f2bf(float f) {
  union { float f; uint32_t i; } v; v.f = f;
  uint32_t u = v.i;
  u += 0x7fffu + ((u >> 16) & 1u);   // RNE
  return (uint16_t)(u >> 16);
}
DEVFN int imin(int a, int b) { return a < b ? a : b; }

DEVFN void gl_lds16(const void* g, void* l) {
  // async global->LDS, 16B per lane; LDS dst = wave-uniform base + lane*16
  __builtin_amdgcn_global_load_lds(
      (__attribute__((address_space(1))) void*)(void*)g,
      (__attribute__((address_space(3))) void*)l, 16, 0, 0);
}

DEVFN f32x4 mfma16(short8 a, short8 b, f32x4 c) {
  return __builtin_amdgcn_mfma_f32_16x16x32_bf16(a, b, c, 0, 0, 0);
}

// ---------------- workspace layout (bytes) ----------------
static constexpr size_t OFF_XP   = 0;          // bf16 [64][232][232][4]  x: masked, padded(+3), NHWC4
static constexpr size_t OFF_W1T  = 27557888;   // bf16 [7][64][32]        w1t[kh][oc][kw*4+ic]
static constexpr size_t OFF_W2T  = 27586560;   // bf16 [49][768][64]      w2t[kh*7+kw][oc][ic]
static constexpr size_t OFF_Y1   = 32403456;   // bf16 [64][112][112][64] conv1 out (active cells only)
static constexpr size_t OFF_P1   = 135163904;  // bf16 [64][62][62][64]   pool1 out, padded(+3), NHWC
static constexpr size_t OFF_Y2   = 166653952;  // bf16 [64][28][28][768]  conv2 out (active cells only)
static constexpr size_t OFF_LIST = 243724288;  // int [12544] active cell list (b*196+cell)
static constexpr size_t OFF_CNT  = 243774464;  // int count
static constexpr size_t WS_NEED  = 243774468;

// ---------------- stage 0: active-cell list ----------------
__global__ __launch_bounds__(256) void k_list(const int* __restrict__ masks,
                                              int* __restrict__ list, int* __restrict__ count) {
  int gid = blockIdx.x * 256 + threadIdx.x;   // 49*256 = 12544 exactly
  if (masks[gid]) {
    int p = atomicAdd(count, 1);
    list[p] = gid;
  }
}

// ---------------- stage 1: x -> masked bf16 NHWC4 padded ----------------
__global__ __launch_bounds__(256) void k_prep(const float* __restrict__ x, const int* __restrict__ masks,
                                              uint16_t* __restrict__ xp) {
  int gid = blockIdx.x * 256 + threadIdx.x;   // 64*232*232 = 3,444,736 exactly
  int b = gid / 53824;
  int rc = gid - b * 53824;
  int r2 = rc / 232;
  int c2 = rc - r2 * 232;
  int r = r2 - 3, c = c2 - 3;
  uint16_t o0 = 0, o1 = 0, o2 = 0;
  if ((unsigned)r < 224u && (unsigned)c < 224u) {
    if (masks[b * 196 + (r >> 4) * 14 + (c >> 4)]) {
      const float* px = x + (((size_t)b * 3) * 224 + r) * 224 + c;
      o0 = f2bf(px[0]);
      o1 = f2bf(px[50176]);
      o2 = f2bf(px[100352]);
    }
  }
  ushort4 o; o.x = o0; o.y = o1; o.z = o2; o.w = 0;
  *(ushort4*)(xp + (size_t)gid * 4) = o;
}

// ---------------- stage 2: weight transforms ----------------
__global__ __launch_bounds__(256) void k_wt(const float* __restrict__ w1, const float* __restrict__ w2,
                                            uint16_t* __restrict__ w1t, uint16_t* __restrict__ w2t) {
  int gid = blockIdx.x * 256 + threadIdx.x;   // 14336 + 2408448 = 2,422,784 exactly
  if (gid < 14336) {
    int kh = gid / 2048; int r = gid - kh * 2048;
    int oc = r >> 5, slot = r & 31;
    int kw = slot >> 2, ic = slot & 3;
    float v = 0.f;
    if (kw < 7 && ic < 3) v = w1[((oc * 3 + ic) * 7 + kh) * 7 + kw];
    w1t[gid] = f2bf(v);
  } else {
    int g2 = gid - 14336;
    int khw = g2 / 49152; int r = g2 - khw * 49152;
    int oc = r >> 6, ic = r & 63;
    int kh = khw / 7, kw = khw - kh * 7;
    w2t[g2] = f2bf(w2[((oc * 64 + ic) * 7 + kh) * 7 + kw]);
  }
}

// ---------------- stage 3: conv1 (7x7 s2) via MFMA, active cells only ----------------
// M-tile = 2 cells * 64 positions = 128, N = 64 oc, K = 7 kh-steps of 32 (8 kw-slots * 4 ch)
// LDS rows are 64 B = 4x16B chunks; chunk position XOR-swizzled by (row&3) to spread banks.
__global__ __launch_bounds__(256) void k_conv1(const uint16_t* __restrict__ xp, const uint16_t* __restrict__ w1t,
                                               const int* __restrict__ list, const int* __restrict__ count,
                                               uint16_t* __restrict__ y1) {
  __shared__ uint16_t sB[7 * 64 * 32];   // 28 KB: whole w1t resident
  __shared__ uint16_t sA[128 * 32];      // 8 KB
  __shared__ int sc[2];

  int cnt = *count;
  int blk = blockIdx.x;
  if (blk * 2 >= cnt) return;
  int tid = threadIdx.x, lane = tid & 63, wave = tid >> 6;
  int csw = (lane & 3) ^ ((lane >> 2) & 3);   // swizzled 16B-chunk index for staging

  // stage all of w1t -> sB (1792 x 16B chunks), chunk-swizzled by oc&3
  {
    const char* wg = (const char*)w1t;
    char* wl = (char*)sB;
#pragma unroll
    for (int t = 0; t < 7; ++t) {
      int ldsoff = t * 4096 + wave * 1024;
      int goff = t * 4096 + (wave * 16 + (lane >> 2)) * 64 + csw * 16;
      gl_lds16(wg + goff, wl + ldsoff);
    }
  }
  if (tid < 2) sc[tid] = list[imin(blk * 2 + tid, cnt - 1)];
  __syncthreads();

  // per-lane A staging addresses (2 rows per lane), chunk-swizzled
  const char* gA[2];
#pragma unroll
  for (int t = 0; t < 2; ++t) {
    int r = wave * 32 + t * 16 + (lane >> 2);
    int cell = sc[r >> 6];
    int b = cell / 196, cc = cell - b * 196;
    int ci = cc / 14, cj = cc - ci * 14;
    int p = r & 63;
    int oh = ci * 8 + (p >> 3), ow = cj * 8 + (p & 7);
    gA[t] = (const char*)xp + (((size_t)(b * 232 + 2 * oh)) * 232 + 2 * ow) * 8 + csw * 16;
  }

  f32x4 acc[2][4];
#pragma unroll
  for (int i = 0; i < 2; ++i)
#pragma unroll
    for (int j = 0; j < 4; ++j) acc[i][j] = f32x4{0.f, 0.f, 0.f, 0.f};

  int wm = wave * 32;
  int mrow = lane & 15, kg = lane >> 4;
  int sw1 = mrow & 3;

#pragma unroll 1
  for (int kh = 0; kh < 7; ++kh) {
    char* la = (char*)sA + wm * 64;
    gl_lds16(gA[0] + kh * 1856, la);
    gl_lds16(gA[1] + kh * 1856, la + 1024);
    __syncthreads();
    const uint16_t* Bk = sB + kh * 2048;
    int ksw = (kg ^ sw1) * 8;
    short8 a0 = *(const short8*)(sA + (wm + mrow) * 32 + ksw);
    short8 a1 = *(const short8*)(sA + (wm + 16 + mrow) * 32 + ksw);
#pragma unroll
    for (int j = 0; j < 4; ++j) {
      short8 bj = *(const short8*)(Bk + (16 * j + mrow) * 32 + ksw);
      acc[0][j] = mfma16(a0, bj, acc[0][j]);
      acc[1][j] = mfma16(a1, bj, acc[1][j]);
    }
    __syncthreads();
  }

  // epilogue: relu, write NHWC bf16 (mask is 1 on all rows here)
#pragma unroll
  for (int i = 0; i < 2; ++i) {
    int rbase = wm + 16 * i;
    int cellidx = blk * 2 + (rbase >> 6);
    if (cellidx >= cnt) continue;
    int cell = sc[rbase >> 6];
    int b = cell / 196, cc = cell - b * 196;
    int ci = cc / 14, cj = cc - ci * 14;
#pragma unroll
    for (int j = 0; j < 4; ++j) {
      int oc = 16 * j + mrow;
#pragma unroll
      for (int r = 0; r < 4; ++r) {
        int row = rbase + kg * 4 + r;
        int p = row & 63;
        int oh = ci * 8 + (p >> 3), ow = cj * 8 + (p & 7);
        float v = acc[i][j][r];
        v = v > 0.f ? v : 0.f;
        y1[(((size_t)(b * 112 + oh)) * 112 + ow) * 64 + oc] = f2bf(v);
      }
    }
  }
}

// ---------------- stage 4: MaxBlurPool1 (112 -> 56), mask-aware, writes padded p1 ----------------
__global__ __launch_bounds__(256) void k_pool1(const uint16_t* __restrict__ y1, const int* __restrict__ masks,
                                               uint16_t* __restrict__ p1) {
  __shared__ uint16_t sY[18 * 18 * 64];  // 41,472 B
  int b = blockIdx.y;
  int tile = blockIdx.x;                 // 64 tiles of 8x8 over padded 62x62
  int tr = tile >> 3, tc = tile & 7;
  int pr0 = tr * 8, pc0 = tc * 8;
  int R0 = 2 * pr0 - 7, C0 = 2 * pc0 - 7;  // staged y1 origin (padded coords -3, then 2*oh-1)
  int tid = threadIdx.x;
  const int* mb = masks + b * 196;

  for (int idx = tid; idx < 2592; idx += 256) {   // 324 pixels * 8 chunks
    int pix = idx >> 3, ch = idx & 7;
    int pr = pix / 18, pc = pix - pr * 18;
    int r = R0 + pr, c = C0 + pc;
    short8 v = {0, 0, 0, 0, 0, 0, 0, 0};
    if ((unsigned)r < 112u && (unsigned)c < 112u && mb[(r >> 3) * 14 + (c >> 3)])
      v = *(const short8*)(y1 + (((size_t)(b * 112 + r)) * 112 + c) * 64 + ch * 8);
    *(short8*)(sY + ((size_t)(pr * 18 + pc)) * 64 + ch * 8) = v;
  }
  __syncthreads();

  for (int it = tid; it < 512; it += 256) {
    int opix = it >> 3, ch = it & 7;
    int lr = opix >> 3, lc = opix & 7;
    int pr = pr0 + lr, pc = pc0 + lc;
    if (pr >= 62 || pc >= 62) continue;
    int oh = pr - 3, ow = pc - 3;
    float acc[8] = {0.f, 0.f, 0.f, 0.f, 0.f, 0.f, 0.f, 0.f};
    if ((unsigned)oh < 56u && (unsigned)ow < 56u) {
      float hm_prev[3][8];
#pragma unroll
      for (int dd = 0; dd < 4; ++dd) {
        float yv[4][8];
        const uint16_t* src = sY + ((size_t)((2 * lr + dd) * 18 + 2 * lc)) * 64 + ch * 8;
#pragma unroll
        for (int e = 0; e < 4; ++e) {
          short8 t8 = *(const short8*)(src + e * 64);
#pragma unroll
          for (int k = 0; k < 8; ++k) yv[e][k] = bf2f((uint16_t)t8[k]);
        }
        float hm[3][8];
#pragma unroll
        for (int e = 0; e < 3; ++e) {
          int qc = 2 * ow - 1 + e;
          float cv = ((unsigned)qc <= 110u) ? 1.f : 0.f;
#pragma unroll
          for (int k = 0; k < 8; ++k) hm[e][k] = cv * fmaxf(yv[e][k], yv[e + 1][k]);
        }
        if (dd > 0) {
          int d = dd - 1;
          int qr = 2 * oh - 1 + d;
          if ((unsigned)qr <= 110u) {
            float wd = (d == 1) ? 2.f : 1.f;
#pragma unroll
            for (int e = 0; e < 3; ++e) {
              float w = wd * ((e == 1) ? 2.f : 1.f);
#pragma unroll
              for (int k = 0; k < 8; ++k) acc[k] += w * fmaxf(hm_prev[e][k], hm[e][k]);
            }
          }
        }
#pragma unroll
        for (int e = 0; e < 3; ++e)
#pragma unroll
          for (int k = 0; k < 8; ++k) hm_prev[e][k] = hm[e][k];
      }
#pragma unroll
      for (int k = 0; k < 8; ++k) acc[k] *= (1.f / 16.f);
    }
    short8 o;
#pragma unroll
    for (int k = 0; k < 8; ++k) o[k] = (short)f2bf(acc[k]);
    *(short8*)(p1 + (((size_t)(b * 62 + pr)) * 62 + pc) * 64 + ch * 8) = o;
  }
}

// ---------------- stage 5: conv2 (7x7 s2) via MFMA, active cells only ----------------
// M-tile = 32 cells * 4 positions = 128, N-tile = 128 of 768 oc, K = 49 steps of 64 (ic)
// LDS rows are 128 B = 8x16B chunks; chunk position XOR-swizzled by (row&7): a 16-lane
// fragment read (row stride 128 B == 32 banks) spreads over all 8 chunk quads -> 2-way (free).
__global__ __launch_bounds__(256) void k_conv2(const uint16_t* __restrict__ p1, const uint16_t* __restrict__ w2t,
                                               const int* __restrict__ list, const int* __restrict__ count,
                                               uint16_t* __restrict__ y2) {
  __shared__ uint16_t sA[128 * 64];   // 16 KB  A[row][ic]
  __shared__ uint16_t sBt[128 * 64];  // 16 KB  B^T[oc][ic]
  __shared__ int sc[32];

  int cnt = *count;
  int mt = blockIdx.x;
  if (mt * 32 >= cnt) return;
  int tid = threadIdx.x, lane = tid & 63, wave = tid >> 6;
  int ocb = blockIdx.y * 128;
  int csw = (lane & 7) ^ ((lane >> 3) & 7);   // swizzled 16B-chunk index for staging

  if (tid < 32) sc[tid] = list[imin(mt * 32 + tid, cnt - 1)];
  __syncthreads();

  const char* gA[4]; const char* gB[4];
#pragma unroll
  for (int t = 0; t < 4; ++t) {
    int r = wave * 32 + t * 8 + (lane >> 3);
    int cell = sc[r >> 2];
    int b = cell / 196, cc = cell - b * 196;
    int ci = cc / 14, cj = cc - ci * 14;
    int p = r & 3;
    int oh = 2 * ci + (p >> 1), ow = 2 * cj + (p & 1);
    gA[t] = (const char*)p1 + (((size_t)(b * 62 + 2 * oh)) * 62 + 2 * ow) * 128 + csw * 16;
    int ocr = ocb + wave * 32 + t * 8 + (lane >> 3);
    gB[t] = (const char*)w2t + (size_t)ocr * 128 + csw * 16;
  }

  f32x4 acc[4][4];
#pragma unroll
  for (int i = 0; i < 4; ++i)
#pragma unroll
    for (int j = 0; j < 4; ++j) acc[i][j] = f32x4{0.f, 0.f, 0.f, 0.f};

  int wm = (wave >> 1) * 64, wn = (wave & 1) * 64;
  int mrow = lane & 15, kg = lane >> 4;
  int sw = mrow & 7;
  int kh = 0, kw = 0;

#pragma unroll 1
  for (int it = 0; it < 49; ++it) {
    size_t offA = (size_t)(kh * 62 + kw) * 128;
    size_t offB = (size_t)it * 98304;   // 768*128 B per (kh,kw) slice
    char* la = (char*)sA + (wave * 32) * 128;
    char* lb = (char*)sBt + (wave * 32) * 128;
#pragma unroll
    for (int t = 0; t < 4; ++t) {
      gl_lds16(gA[t] + offA, la + t * 1024);
      gl_lds16(gB[t] + offB, lb + t * 1024);
    }
    __syncthreads();
#pragma unroll
    for (int ks = 0; ks < 2; ++ks) {
      int koff = ((ks * 4 + kg) ^ sw) * 8;
      short8 a[4], bb[4];
#pragma unroll
      for (int i = 0; i < 4; ++i)
        a[i] = *(const short8*)(sA + (wm + 16 * i + mrow) * 64 + koff);
#pragma unroll
      for (int j = 0; j < 4; ++j)
        bb[j] = *(const short8*)(sBt + (wn + 16 * j + mrow) * 64 + koff);
#pragma unroll
      for (int i = 0; i < 4; ++i)
#pragma unroll
        for (int j = 0; j < 4; ++j)
          acc[i][j] = mfma16(a[i], bb[j], acc[i][j]);
    }
    __syncthreads();
    if (++kw == 7) { kw = 0; ++kh; }
  }

  // epilogue: relu, write y2 NHWC bf16 (active rows only)
#pragma unroll
  for (int i = 0; i < 4; ++i) {
    int rbase = wm + 16 * i;
    int cellslot = (rbase >> 2) + kg;
    int cellidx = mt * 32 + cellslot;
    if (cellidx >= cnt) continue;
    int cell = sc[cellslot];
    int b = cell / 196, cc = cell - b * 196;
    int ci = cc / 14, cj = cc - ci * 14;
#pragma unroll
    for (int j = 0; j < 4; ++j) {
      int oc = ocb + wn + 16 * j + mrow;
#pragma unroll
      for (int r = 0; r < 4; ++r) {
        int oh = 2 * ci + (r >> 1), ow = 2 * cj + (r & 1);
        float v = acc[i][j][r];
        v = v > 0.f ? v : 0.f;
        y2[(((size_t)(b * 784)) + oh * 28 + ow) * 768 + oc] = f2bf(v);
      }
    }
  }
}

// ---------------- stage 6: MaxBlurPool2 (28 -> 14) + transpose to [B,196,768] fp32 ----------------
// Block = (ch-chunk of 128, output row pi, batch b). Stage the 4x28x128ch input window in LDS
// with 16B coalesced mask-gated loads, then 7 outputs/thread from LDS. Low VGPR, high occupancy.
__global__ __launch_bounds__(256) void k_pool2(const uint16_t* __restrict__ y2, const int* __restrict__ masks,
                                               float* __restrict__ out) {
  __shared__ uint16_t sY[4 * 28 * 128];   // 28,672 B
  int chunk = blockIdx.x, pi = blockIdx.y, b = blockIdx.z;
  int ch0 = chunk * 128;
  int tid = threadIdx.x;
  const int* mb = masks + b * 196;

  // stage 4 rows (r = 2*pi-1+k) x 28 cols x 128 ch
  for (int idx = tid; idx < 1792; idx += 256) {
    int rc = idx >> 4;          // 0..111  (k*28 + c)
    int sub = idx & 15;         // 16B chunk within the 128-ch slab
    int k = rc / 28, c = rc - k * 28;
    int r = 2 * pi - 1 + k;
    short8 v = {0, 0, 0, 0, 0, 0, 0, 0};
    if ((unsigned)r < 28u && mb[(r >> 1) * 14 + (c >> 1)])
      v = *(const short8*)(y2 + (((size_t)(b * 784)) + r * 28 + c) * 768 + ch0 + sub * 8);
    *(short8*)(sY + ((size_t)(k * 28 + c)) * 128 + sub * 8) = v;
  }
  __syncthreads();

  // compute 14 pj x 128 ch outputs
  for (int idx = tid; idx < 1792; idx += 256) {
    int pj = idx >> 7, ch = idx & 127;
    float v[4][4];   // [k][e] rows k=0..3, cols 2*pj-1+e
#pragma unroll
    for (int e = 0; e < 4; ++e) {
      int col = 2 * pj - 1 + e;
      bool cv = (unsigned)col < 28u;
#pragma unroll
      for (int k = 0; k < 4; ++k)
        v[k][e] = cv ? bf2f(sY[((size_t)(k * 28 + col)) * 128 + ch]) : 0.f;
    }
    float acc = 0.f;
#pragma unroll
    for (int d = 0; d < 3; ++d) {
      int q = 2 * pi - 1 + d;
      float gd = ((unsigned)q <= 26u) ? ((d == 1) ? 2.f : 1.f) : 0.f;
      float s = 0.f;
#pragma unroll
      for (int e = 0; e < 3; ++e) {
        int q2 = 2 * pj - 1 + e;
        float ge = ((unsigned)q2 <= 26u) ? ((e == 1) ? 2.f : 1.f) : 0.f;
        float m = fmaxf(fmaxf(v[d][e], v[d + 1][e]), fmaxf(v[d][e + 1], v[d + 1][e + 1]));
        s += ge * m;
      }
      acc += gd * s;
    }
    out[(((size_t)(b * 196)) + pi * 14 + pj) * 768 + ch0 + ch] = acc * (1.f / 16.f);
  }
}

// ---------------- launcher ----------------
extern "C" void kernel_launch(void* const* d_in, const int* in_sizes, int n_in,
                              void* d_out, int out_size, void* d_ws, size_t ws_size,
                              hipStream_t stream) {
  const float* x     = (const float*)d_in[0];
  const int*   masks = (const int*)d_in[1];
  const float* w1    = (const float*)d_in[2];
  const float* w2    = (const float*)d_in[3];

  char* ws = (char*)d_ws;
  if (ws_size < WS_NEED) return;  // fail loudly (output stays poisoned) rather than corrupt memory

  uint16_t* xp  = (uint16_t*)(ws + OFF_XP);
  uint16_t* w1t = (uint16_t*)(ws + OFF_W1T);
  uint16_t* w2t = (uint16_t*)(ws + OFF_W2T);
  uint16_t* y1  = (uint16_t*)(ws + OFF_Y1);
  uint16_t* p1  = (uint16_t*)(ws + OFF_P1);
  uint16_t* y2  = (uint16_t*)(ws + OFF_Y2);
  int* list     = (int*)(ws + OFF_LIST);
  int* cnt      = (int*)(ws + OFF_CNT);

  hipMemsetAsync(cnt, 0, 4, stream);
  k_list<<<49, 256, 0, stream>>>(masks, list, cnt);
  k_prep<<<13456, 256, 0, stream>>>(x, masks, xp);
  k_wt<<<9464, 256, 0, stream>>>(w1, w2, w1t, w2t);
  k_conv1<<<6272, 256, 0, stream>>>(xp, w1t, list, cnt, y1);
  k_pool1<<<dim3(64, 64), 256, 0, stream>>>(y1, masks, p1);
  k_conv2<<<dim3(392, 6), 256, 0, stream>>>(p1, w2t, list, cnt, y2);
  k_pool2<<<dim3(6, 14, 64), 256, 0, stream>>>(y2, masks, (float*)d_out);
}